// Round 4
// baseline (1308.877 us; speedup 1.0000x reference)
//
#include <hip/hip_runtime.h>
#include <stdint.h>
#include <stddef.h>

// W4A8 fake-quant SwiGLU MLP for MI355X (gfx950).
// Exact-integer reformulation: fake-quant values are int*scale, so every
// matmul is an int8 x int4 integer GEMM (exact in i32/f32) times rank-1 scales.
// GEMMs: mfma_i32_16x16x64_i8, global_load_lds width-16,
// XOR-swizzled LDS (slot = (quad + (row>>1)) & 3) for conflict-free b128 reads.
//
// R1: gemm1 (256,4)->(256,2): accumulator spill eliminated, 2700 -> 527 us.
// R2: XCD swizzle (gemm1 527->499); gemm2 (256,2) neutral (no spill there).
// R3: gemm2 tile 128x256 (32 MFMA/wave/K-step); merged 4 quant launches.
// R4: (a) 2-phase double-buffered LDS in both GEMMs: STAGE(t+1) issued into
//     the alternate buffer BEFORE computing tile t -> global_load_lds latency
//     hides under ds_read+MFMA; one barrier per K-step instead of two.
//     (b) h row-absmax fused into gemm1 epilogue (shuffle-reduce + atomicMax
//     on int bits of nonneg f32) -> quant_h is single-pass (-180 MB read).

using i32x4 = __attribute__((ext_vector_type(4))) int;

#define BM 128
#define BN 128
#define BN2 256
#define BK 64

__device__ __forceinline__ void gl2lds16(const void* gptr, void* lptr) {
  __builtin_amdgcn_global_load_lds(
      (const __attribute__((address_space(1))) uint32_t*)gptr,
      (__attribute__((address_space(3))) uint32_t*)lptr, 16, 0, 0);
}

// ---------------------------------------------------------------------------
// Merged per-row symmetric fake-quant for all four inputs in ONE launch.
// blockIdx segments: [0,4096) x rows | [4096,15104) Wg | [15104,26112) Wu |
// [26112,30208) Wd. Also zero-inits hmax[row] in the x segment.
// ---------------------------------------------------------------------------
__global__ void quant_all_kernel(
    const float* __restrict__ x, const float* __restrict__ Wg,
    const float* __restrict__ Wu, const float* __restrict__ Wd,
    int8_t* __restrict__ xq, int8_t* __restrict__ wgq,
    int8_t* __restrict__ wuq, int8_t* __restrict__ wdq,
    float* __restrict__ sx, float* __restrict__ swg,
    float* __restrict__ swu, float* __restrict__ swd,
    int* __restrict__ hmax) {
  const int b = blockIdx.x;
  const float* src;
  int8_t* dst;
  float* scales;
  int cols, row;
  float qmax, qmin;
  if (b < 4096) {
    src = x; dst = xq; scales = sx; cols = 4096; row = b;
    qmax = 127.0f; qmin = -128.0f;
    if (threadIdx.x == 0) hmax[row] = 0;  // init for gemm1's atomicMax
  } else if (b < 4096 + 11008) {
    src = Wg; dst = wgq; scales = swg; cols = 4096; row = b - 4096;
    qmax = 7.0f; qmin = -8.0f;
  } else if (b < 4096 + 22016) {
    src = Wu; dst = wuq; scales = swu; cols = 4096; row = b - 15104;
    qmax = 7.0f; qmin = -8.0f;
  } else {
    src = Wd; dst = wdq; scales = swd; cols = 11008; row = b - 26112;
    qmax = 7.0f; qmin = -8.0f;
  }
  const int n4 = cols >> 2;
  const float4* s4 = (const float4*)(src + (size_t)row * cols);
  float amax = 0.0f;
  for (int i = threadIdx.x; i < n4; i += blockDim.x) {
    float4 v = s4[i];
    amax = fmaxf(amax, fmaxf(fmaxf(fabsf(v.x), fabsf(v.y)),
                             fmaxf(fabsf(v.z), fabsf(v.w))));
  }
#pragma unroll
  for (int off = 32; off > 0; off >>= 1)
    amax = fmaxf(amax, __shfl_xor(amax, off, 64));
  __shared__ float wmax[4];
  if ((threadIdx.x & 63) == 0) wmax[threadIdx.x >> 6] = amax;
  __syncthreads();
  const float scale =
      fmaxf(fmaxf(fmaxf(wmax[0], wmax[1]), fmaxf(wmax[2], wmax[3])) / qmax,
            1e-8f);
  if (threadIdx.x == 0) scales[row] = scale;
  char4* d4 = (char4*)(dst + (size_t)row * cols);
  for (int i = threadIdx.x; i < n4; i += blockDim.x) {
    float4 v = s4[i];
    char4 q;
    q.x = (char)(int)fminf(fmaxf(rintf(v.x / scale), qmin), qmax);
    q.y = (char)(int)fminf(fmaxf(rintf(v.y / scale), qmin), qmax);
    q.z = (char)(int)fminf(fmaxf(rintf(v.z / scale), qmin), qmax);
    q.w = (char)(int)fminf(fmaxf(rintf(v.w / scale), qmin), qmax);
    d4[i] = q;
  }
}

// Single-pass per-row quant of h: absmax comes from gemm1's fused atomicMax.
__global__ void quant_h_kernel(const float* __restrict__ h,
                               int8_t* __restrict__ hq,
                               float* __restrict__ sh,
                               const int* __restrict__ hmax, int cols) {
  const int row = blockIdx.x;
  const float amax = __int_as_float(hmax[row]);
  const float scale = fmaxf(amax / 127.0f, 1e-8f);
  if (threadIdx.x == 0) sh[row] = scale;
  const int n4 = cols >> 2;
  const float4* s4 = (const float4*)(h + (size_t)row * cols);
  char4* d4 = (char4*)(hq + (size_t)row * cols);
  for (int i = threadIdx.x; i < n4; i += blockDim.x) {
    float4 v = s4[i];
    char4 q;
    q.x = (char)(int)fminf(fmaxf(rintf(v.x / scale), -128.0f), 127.0f);
    q.y = (char)(int)fminf(fmaxf(rintf(v.y / scale), -128.0f), 127.0f);
    q.z = (char)(int)fminf(fmaxf(rintf(v.z / scale), -128.0f), 127.0f);
    q.w = (char)(int)fminf(fmaxf(rintf(v.w / scale), -128.0f), 127.0f);
    d4[i] = q;
  }
}

// Bijective XCD-aware remap of the linear block id (requires nwg % 8 == 0).
__device__ __forceinline__ int xcd_swizzle(int lid, int nwg) {
  const int cpx = nwg >> 3;
  return (lid & 7) * cpx + (lid >> 3);
}

// Fused gate+up GEMM: acc_g = xq @ Wg^T, acc_u = xq @ Wu^T (int32 exact),
// epilogue h = silu(acc_g*sx*swg) * (acc_u*sx*swu) -> hbuf (f32),
// plus per-row |h| max -> atomicMax(hmax[row]).
// 2-phase double-buffered LDS: 48 KB/block, one barrier per K-step.
__global__ __launch_bounds__(256, 2) void gemm1_kernel(
    const int8_t* __restrict__ xq, const int8_t* __restrict__ wgq,
    const int8_t* __restrict__ wuq, const float* __restrict__ sx,
    const float* __restrict__ swg, const float* __restrict__ swu,
    float* __restrict__ hbuf, int* __restrict__ hmax, int M, int N, int K) {
  __shared__ __align__(16) int8_t sA[2][BM * BK];
  __shared__ __align__(16) int8_t sBg[2][BN * BK];
  __shared__ __align__(16) int8_t sBu[2][BN * BK];

  const int tid = threadIdx.x;
  const int lane = tid & 63;
  const int quad = lane >> 4;
  const int l16 = lane & 15;
  const int wave = tid >> 6;
  const int wm = wave >> 1;
  const int wn = wave & 1;

  const int nwg = gridDim.x * gridDim.y;
  const int lid = xcd_swizzle(blockIdx.y * gridDim.x + blockIdx.x, nwg);
  const int n0 = (lid % gridDim.x) * BN;
  const int m0 = (lid / gridDim.x) * BM;

  i32x4 accg[4][4] = {};
  i32x4 accu[4][4] = {};

#define STAGE1(buf, kk)                                                       \
  {                                                                           \
    _Pragma("unroll") for (int it = 0; it < 2; ++it) {                        \
      const int c = tid + it * 256;                                           \
      const int r = c >> 2;                                                   \
      const int s = c & 3;                                                    \
      const int kc = ((s - (r >> 1)) & 3) << 4;                               \
      gl2lds16(xq + (size_t)(m0 + r) * K + ((kk) + kc), sA[buf] + c * 16);    \
      gl2lds16(wgq + (size_t)(n0 + r) * K + ((kk) + kc), sBg[buf] + c * 16);  \
      gl2lds16(wuq + (size_t)(n0 + r) * K + ((kk) + kc), sBu[buf] + c * 16);  \
    }                                                                         \
  }

  STAGE1(0, 0);
  __syncthreads();  // implicit vmcnt(0): tile 0 resident
  int cur = 0;
  for (int k0 = 0; k0 < K; k0 += BK) {
    if (k0 + BK < K) STAGE1(cur ^ 1, k0 + BK);  // prefetch next tile

    i32x4 af[4];
#pragma unroll
    for (int i = 0; i < 4; ++i) {
      const int ar = wm * 64 + i * 16 + l16;
      af[i] = *(const i32x4*)(sA[cur] + ar * BK + (((quad + (ar >> 1)) & 3) << 4));
    }
#pragma unroll
    for (int j = 0; j < 4; ++j) {
      const int br = wn * 64 + j * 16 + l16;
      const int bo = br * BK + (((quad + (br >> 1)) & 3) << 4);
      i32x4 bg = *(const i32x4*)(sBg[cur] + bo);
      i32x4 bu = *(const i32x4*)(sBu[cur] + bo);
#pragma unroll
      for (int i = 0; i < 4; ++i) {
        accg[i][j] = __builtin_amdgcn_mfma_i32_16x16x64_i8(af[i], bg, accg[i][j], 0, 0, 0);
        accu[i][j] = __builtin_amdgcn_mfma_i32_16x16x64_i8(af[i], bu, accu[i][j], 0, 0, 0);
      }
    }
    __syncthreads();  // drains vmcnt (prefetched tile ready) + LDS reuse safe
    cur ^= 1;
  }
#undef STAGE1

  float sg[4], su[4];
#pragma unroll
  for (int j = 0; j < 4; ++j) {
    const int col = n0 + wn * 64 + j * 16 + l16;
    sg[j] = swg[col];
    su[j] = swu[col];
  }
#pragma unroll
  for (int i = 0; i < 4; ++i) {
#pragma unroll
    for (int r = 0; r < 4; ++r) {
      const int row = m0 + wm * 64 + i * 16 + quad * 4 + r;
      const float s_x = sx[row];
      float rmax = 0.0f;
#pragma unroll
      for (int j = 0; j < 4; ++j) {
        const int col = n0 + wn * 64 + j * 16 + l16;
        const float g = (float)accg[i][j][r] * s_x * sg[j];
        const float u = (float)accu[i][j][r] * s_x * su[j];
        const float hv = (g / (1.0f + expf(-g))) * u;  // silu(g)*u
        hbuf[(size_t)row * N + col] = hv;
        rmax = fmaxf(rmax, fabsf(hv));
      }
      // reduce |h| max across the 16 lanes holding this row's columns
#pragma unroll
      for (int off = 8; off > 0; off >>= 1)
        rmax = fmaxf(rmax, __shfl_xor(rmax, off, 64));
      if (l16 == 0)
        atomicMax(hmax + row, __float_as_int(rmax));  // nonneg f32: int-mono
    }
  }
}

// Down-projection GEMM: out = (hq @ Wd^T) * sh[m] * swd[n]
// 128x256 tile, per-wave 64x128 (acc[4][8] = 128 VGPR), 2-phase dbuf LDS.
__global__ __launch_bounds__(256, 2) void gemm2_kernel(
    const int8_t* __restrict__ hq, const int8_t* __restrict__ wdq,
    const float* __restrict__ sh, const float* __restrict__ swd,
    float* __restrict__ out, int M, int N, int K) {
  __shared__ __align__(16) int8_t sA[2][BM * BK];    // 2 x 8 KB
  __shared__ __align__(16) int8_t sB[2][BN2 * BK];   // 2 x 16 KB

  const int tid = threadIdx.x;
  const int lane = tid & 63;
  const int quad = lane >> 4;
  const int l16 = lane & 15;
  const int wave = tid >> 6;
  const int wm = wave >> 1;   // 0..1: 64-row group
  const int wn = wave & 1;    // 0..1: 128-col group

  const int nwg = gridDim.x * gridDim.y;
  const int lid = xcd_swizzle(blockIdx.y * gridDim.x + blockIdx.x, nwg);
  const int n0 = (lid % gridDim.x) * BN2;
  const int m0 = (lid / gridDim.x) * BM;

  i32x4 acc[4][8] = {};

#define STAGE2(buf, kk)                                                       \
  {                                                                           \
    _Pragma("unroll") for (int it = 0; it < 2; ++it) {                        \
      const int c = tid + it * 256;                                           \
      const int r = c >> 2;                                                   \
      const int s = c & 3;                                                    \
      const int kc = ((s - (r >> 1)) & 3) << 4;                               \
      gl2lds16(hq + (size_t)(m0 + r) * K + ((kk) + kc), sA[buf] + c * 16);    \
    }                                                                         \
    _Pragma("unroll") for (int it = 0; it < 4; ++it) {                        \
      const int c = tid + it * 256;                                           \
      const int r = c >> 2;                                                   \
      const int s = c & 3;                                                    \
      const int kc = ((s - (r >> 1)) & 3) << 4;                               \
      gl2lds16(wdq + (size_t)(n0 + r) * K + ((kk) + kc), sB[buf] + c * 16);   \
    }                                                                         \
  }

  STAGE2(0, 0);
  __syncthreads();
  int cur = 0;
  for (int k0 = 0; k0 < K; k0 += BK) {
    if (k0 + BK < K) STAGE2(cur ^ 1, k0 + BK);

    i32x4 af[4];
#pragma unroll
    for (int i = 0; i < 4; ++i) {
      const int ar = wm * 64 + i * 16 + l16;
      af[i] = *(const i32x4*)(sA[cur] + ar * BK + (((quad + (ar >> 1)) & 3) << 4));
    }
#pragma unroll
    for (int j = 0; j < 8; ++j) {
      const int br = wn * 128 + j * 16 + l16;
      i32x4 bf = *(const i32x4*)(sB[cur] + br * BK + (((quad + (br >> 1)) & 3) << 4));
#pragma unroll
      for (int i = 0; i < 4; ++i)
        acc[i][j] = __builtin_amdgcn_mfma_i32_16x16x64_i8(af[i], bf, acc[i][j], 0, 0, 0);
    }
    __syncthreads();
    cur ^= 1;
  }
#undef STAGE2

  float sn[8];
#pragma unroll
  for (int j = 0; j < 8; ++j) sn[j] = swd[n0 + wn * 128 + j * 16 + l16];
#pragma unroll
  for (int i = 0; i < 4; ++i) {
#pragma unroll
    for (int r = 0; r < 4; ++r) {
      const int row = m0 + wm * 64 + i * 16 + quad * 4 + r;
      const float s_m = sh[row];
#pragma unroll
      for (int j = 0; j < 8; ++j) {
        const int col = n0 + wn * 128 + j * 16 + l16;
        out[(size_t)row * N + col] = (float)acc[i][j][r] * s_m * sn[j];
      }
    }
  }
}

extern "C" void kernel_launch(void* const* d_in, const int* in_sizes, int n_in,
                              void* d_out, int out_size, void* d_ws, size_t ws_size,
                              hipStream_t stream) {
  const float* x  = (const float*)d_in[0];   // [2,2048,4096]
  const float* Wg = (const float*)d_in[1];   // [11008,4096]
  const float* Wu = (const float*)d_in[2];   // [11008,4096]
  const float* Wd = (const float*)d_in[3];   // [4096,11008]
  float* out = (float*)d_out;                // [2,2048,4096] f32

  const int M = 4096;   // B*S
  const int D = 4096;
  const int F = 11008;

  // workspace layout (~378 MB total), all offsets 16B-aligned
  uint8_t* ws = (uint8_t*)d_ws;
  size_t off = 0;
  int8_t* xq  = (int8_t*)(ws + off); off += (size_t)M * D;      // 16 MB
  int8_t* wgq = (int8_t*)(ws + off); off += (size_t)F * D;      // 45 MB
  int8_t* wuq = (int8_t*)(ws + off); off += (size_t)F * D;      // 45 MB
  int8_t* wdq = (int8_t*)(ws + off); off += (size_t)D * F;      // 45 MB
  int8_t* hq  = (int8_t*)(ws + off); off += (size_t)M * F;      // 45 MB
  float* hbuf = (float*)(ws + off);  off += (size_t)M * F * 4;  // 180 MB
  float* sx   = (float*)(ws + off);  off += (size_t)M * 4;
  float* swg  = (float*)(ws + off);  off += (size_t)F * 4;
  float* swu  = (float*)(ws + off);  off += (size_t)F * 4;
  float* swd  = (float*)(ws + off);  off += (size_t)D * 4;
  float* sh   = (float*)(ws + off);  off += (size_t)M * 4;
  int*   hmax = (int*)(ws + off);    off += (size_t)M * 4;

  // One merged quant launch for x, Wg, Wu, Wd (also zeroes hmax).
  hipLaunchKernelGGL(quant_all_kernel, dim3(M + F + F + D), dim3(256), 0,
                     stream, x, Wg, Wu, Wd, xq, wgq, wuq, wdq,
                     sx, swg, swu, swd, hmax);
  hipLaunchKernelGGL(gemm1_kernel, dim3(F / BN, M / BM), dim3(256), 0, stream,
                     xq, wgq, wuq, sx, swg, swu, hbuf, hmax, M, F, D);
  hipLaunchKernelGGL(quant_h_kernel, dim3(M), dim3(256), 0, stream,
                     hbuf, hq, sh, hmax, F);
  hipLaunchKernelGGL(gemm2_kernel, dim3(D / BN2, M / BM), dim3(256), 0, stream,
                     hq, wdq, sh, swd, out, M, D, F);
}

// Round 5
// 1292.553 us; speedup vs baseline: 1.0126x; 1.0126x over previous
//
#include <hip/hip_runtime.h>
#include <stdint.h>
#include <stddef.h>

// W4A8 fake-quant SwiGLU MLP for MI355X (gfx950).
// Exact-integer reformulation: fake-quant values are int*scale, so every
// matmul is an int8 x int4 integer GEMM (exact in i32/f32) times rank-1 scales.
// GEMMs: mfma_i32_16x16x64_i8, global_load_lds width-16,
// XOR-swizzled LDS (slot = (quad + (row>>1)) & 3) for conflict-free b128 reads.
//
// R1: gemm1 (256,4)->(256,2): accumulator spill eliminated, 2700 -> 527 us.
// R2: XCD swizzle (gemm1 527->499); gemm2 (256,2) neutral (no spill there).
// R3: gemm2 tile 128x256 (32 MFMA/wave/K-step); merged 4 quant launches.
// R4: __syncthreads-based 2-phase dbuf REGRESSED (vmcnt(0) drain at every
//     barrier - the m99/m233 result). Kept: fused h-absmax (atomicMax) +
//     single-pass quant_h.
// R5: T3+T4 counted-vmcnt pipeline: 3 LDS buffers, stage 2 tiles ahead,
//     raw s_barrier + s_waitcnt vmcnt(12) (6 loads/thread/tile; never
//     drains to 0 until the tail). setprio(1) around MFMA cluster (T5).

using i32x4 = __attribute__((ext_vector_type(4))) int;

#define BM 128
#define BN 128
#define BN2 256
#define BK 64

__device__ __forceinline__ void gl2lds16(const void* gptr, void* lptr) {
  __builtin_amdgcn_global_load_lds(
      (const __attribute__((address_space(1))) uint32_t*)gptr,
      (__attribute__((address_space(3))) uint32_t*)lptr, 16, 0, 0);
}

// ---------------------------------------------------------------------------
// Merged per-row symmetric fake-quant for all four inputs in ONE launch.
// blockIdx segments: [0,4096) x rows | [4096,15104) Wg | [15104,26112) Wu |
// [26112,30208) Wd. Also zero-inits hmax[row] in the x segment.
// ---------------------------------------------------------------------------
__global__ void quant_all_kernel(
    const float* __restrict__ x, const float* __restrict__ Wg,
    const float* __restrict__ Wu, const float* __restrict__ Wd,
    int8_t* __restrict__ xq, int8_t* __restrict__ wgq,
    int8_t* __restrict__ wuq, int8_t* __restrict__ wdq,
    float* __restrict__ sx, float* __restrict__ swg,
    float* __restrict__ swu, float* __restrict__ swd,
    int* __restrict__ hmax) {
  const int b = blockIdx.x;
  const float* src;
  int8_t* dst;
  float* scales;
  int cols, row;
  float qmax, qmin;
  if (b < 4096) {
    src = x; dst = xq; scales = sx; cols = 4096; row = b;
    qmax = 127.0f; qmin = -128.0f;
    if (threadIdx.x == 0) hmax[row] = 0;  // init for gemm1's atomicMax
  } else if (b < 4096 + 11008) {
    src = Wg; dst = wgq; scales = swg; cols = 4096; row = b - 4096;
    qmax = 7.0f; qmin = -8.0f;
  } else if (b < 4096 + 22016) {
    src = Wu; dst = wuq; scales = swu; cols = 4096; row = b - 15104;
    qmax = 7.0f; qmin = -8.0f;
  } else {
    src = Wd; dst = wdq; scales = swd; cols = 11008; row = b - 26112;
    qmax = 7.0f; qmin = -8.0f;
  }
  const int n4 = cols >> 2;
  const float4* s4 = (const float4*)(src + (size_t)row * cols);
  float amax = 0.0f;
  for (int i = threadIdx.x; i < n4; i += blockDim.x) {
    float4 v = s4[i];
    amax = fmaxf(amax, fmaxf(fmaxf(fabsf(v.x), fabsf(v.y)),
                             fmaxf(fabsf(v.z), fabsf(v.w))));
  }
#pragma unroll
  for (int off = 32; off > 0; off >>= 1)
    amax = fmaxf(amax, __shfl_xor(amax, off, 64));
  __shared__ float wmax[4];
  if ((threadIdx.x & 63) == 0) wmax[threadIdx.x >> 6] = amax;
  __syncthreads();
  const float scale =
      fmaxf(fmaxf(fmaxf(wmax[0], wmax[1]), fmaxf(wmax[2], wmax[3])) / qmax,
            1e-8f);
  if (threadIdx.x == 0) scales[row] = scale;
  char4* d4 = (char4*)(dst + (size_t)row * cols);
  for (int i = threadIdx.x; i < n4; i += blockDim.x) {
    float4 v = s4[i];
    char4 q;
    q.x = (char)(int)fminf(fmaxf(rintf(v.x / scale), qmin), qmax);
    q.y = (char)(int)fminf(fmaxf(rintf(v.y / scale), qmin), qmax);
    q.z = (char)(int)fminf(fmaxf(rintf(v.z / scale), qmin), qmax);
    q.w = (char)(int)fminf(fmaxf(rintf(v.w / scale), qmin), qmax);
    d4[i] = q;
  }
}

// Single-pass per-row quant of h: absmax comes from gemm1's fused atomicMax.
__global__ void quant_h_kernel(const float* __restrict__ h,
                               int8_t* __restrict__ hq,
                               float* __restrict__ sh,
                               const int* __restrict__ hmax, int cols) {
  const int row = blockIdx.x;
  const float amax = __int_as_float(hmax[row]);
  const float scale = fmaxf(amax / 127.0f, 1e-8f);
  if (threadIdx.x == 0) sh[row] = scale;
  const int n4 = cols >> 2;
  const float4* s4 = (const float4*)(h + (size_t)row * cols);
  char4* d4 = (char4*)(hq + (size_t)row * cols);
  for (int i = threadIdx.x; i < n4; i += blockDim.x) {
    float4 v = s4[i];
    char4 q;
    q.x = (char)(int)fminf(fmaxf(rintf(v.x / scale), -128.0f), 127.0f);
    q.y = (char)(int)fminf(fmaxf(rintf(v.y / scale), -128.0f), 127.0f);
    q.z = (char)(int)fminf(fmaxf(rintf(v.z / scale), -128.0f), 127.0f);
    q.w = (char)(int)fminf(fmaxf(rintf(v.w / scale), -128.0f), 127.0f);
    d4[i] = q;
  }
}

// Bijective XCD-aware remap of the linear block id (requires nwg % 8 == 0).
__device__ __forceinline__ int xcd_swizzle(int lid, int nwg) {
  const int cpx = nwg >> 3;
  return (lid & 7) * cpx + (lid >> 3);
}

// Counted waits: 6 loads/thread/tile in both GEMMs; 2 tiles ahead in flight.
__device__ __forceinline__ void wait_tile(int t, int T) {
  if (t + 2 < T) {
    asm volatile("s_waitcnt vmcnt(12)" ::: "memory");
  } else if (t + 1 < T) {
    asm volatile("s_waitcnt vmcnt(6)" ::: "memory");
  } else {
    asm volatile("s_waitcnt vmcnt(0)" ::: "memory");
  }
  __builtin_amdgcn_s_barrier();
  asm volatile("" ::: "memory");
}

// Fused gate+up GEMM: acc_g = xq @ Wg^T, acc_u = xq @ Wu^T (int32 exact),
// epilogue h = silu(acc_g*sx*swg) * (acc_u*sx*swu) -> hbuf (f32),
// plus per-row |h| max -> atomicMax(hmax[row]).
// 3-buffer counted-vmcnt pipeline, 72 KB LDS, 2 blocks/CU.
__global__ __launch_bounds__(256, 2) void gemm1_kernel(
    const int8_t* __restrict__ xq, const int8_t* __restrict__ wgq,
    const int8_t* __restrict__ wuq, const float* __restrict__ sx,
    const float* __restrict__ swg, const float* __restrict__ swu,
    float* __restrict__ hbuf, int* __restrict__ hmax, int M, int N, int K) {
  __shared__ __align__(16) int8_t sA[3][BM * BK];
  __shared__ __align__(16) int8_t sBg[3][BN * BK];
  __shared__ __align__(16) int8_t sBu[3][BN * BK];

  const int tid = threadIdx.x;
  const int lane = tid & 63;
  const int quad = lane >> 4;
  const int l16 = lane & 15;
  const int wave = tid >> 6;
  const int wm = wave >> 1;
  const int wn = wave & 1;

  const int nwg = gridDim.x * gridDim.y;
  const int lid = xcd_swizzle(blockIdx.y * gridDim.x + blockIdx.x, nwg);
  const int n0 = (lid % gridDim.x) * BN;
  const int m0 = (lid / gridDim.x) * BM;

  const int T = K / BK;

  i32x4 accg[4][4] = {};
  i32x4 accu[4][4] = {};

#define STAGE1(buf, kt)                                                       \
  {                                                                           \
    const int kk = (kt)*BK;                                                   \
    _Pragma("unroll") for (int it = 0; it < 2; ++it) {                        \
      const int c = tid + it * 256;                                           \
      const int r = c >> 2;                                                   \
      const int s = c & 3;                                                    \
      const int kc = ((s - (r >> 1)) & 3) << 4;                               \
      gl2lds16(xq + (size_t)(m0 + r) * K + (kk + kc), sA[buf] + c * 16);      \
      gl2lds16(wgq + (size_t)(n0 + r) * K + (kk + kc), sBg[buf] + c * 16);    \
      gl2lds16(wuq + (size_t)(n0 + r) * K + (kk + kc), sBu[buf] + c * 16);    \
    }                                                                         \
  }

  STAGE1(0, 0);
  STAGE1(1, 1);
  STAGE1(2, 2);

  for (int t = 0; t < T; ++t) {
    wait_tile(t, T);  // own tile-t loads done + collective via barrier
    const int cur = t % 3;

    i32x4 af[4];
#pragma unroll
    for (int i = 0; i < 4; ++i) {
      const int ar = wm * 64 + i * 16 + l16;
      af[i] = *(const i32x4*)(sA[cur] + ar * BK + (((quad + (ar >> 1)) & 3) << 4));
    }
    __builtin_amdgcn_s_setprio(1);
#pragma unroll
    for (int j = 0; j < 4; ++j) {
      const int br = wn * 64 + j * 16 + l16;
      const int bo = br * BK + (((quad + (br >> 1)) & 3) << 4);
      i32x4 bg = *(const i32x4*)(sBg[cur] + bo);
      i32x4 bu = *(const i32x4*)(sBu[cur] + bo);
#pragma unroll
      for (int i = 0; i < 4; ++i) {
        accg[i][j] = __builtin_amdgcn_mfma_i32_16x16x64_i8(af[i], bg, accg[i][j], 0, 0, 0);
        accu[i][j] = __builtin_amdgcn_mfma_i32_16x16x64_i8(af[i], bu, accu[i][j], 0, 0, 0);
      }
    }
    __builtin_amdgcn_s_setprio(0);

    asm volatile("" ::: "memory");
    __builtin_amdgcn_s_barrier();   // all waves done reading buf[cur]
    asm volatile("" ::: "memory");
    if (t + 3 < T) STAGE1(cur, t + 3);  // restage the buffer just freed
  }
#undef STAGE1

  float sg[4], su[4];
#pragma unroll
  for (int j = 0; j < 4; ++j) {
    const int col = n0 + wn * 64 + j * 16 + l16;
    sg[j] = swg[col];
    su[j] = swu[col];
  }
#pragma unroll
  for (int i = 0; i < 4; ++i) {
#pragma unroll
    for (int r = 0; r < 4; ++r) {
      const int row = m0 + wm * 64 + i * 16 + quad * 4 + r;
      const float s_x = sx[row];
      float rmax = 0.0f;
#pragma unroll
      for (int j = 0; j < 4; ++j) {
        const int col = n0 + wn * 64 + j * 16 + l16;
        const float g = (float)accg[i][j][r] * s_x * sg[j];
        const float u = (float)accu[i][j][r] * s_x * su[j];
        const float hv = (g / (1.0f + expf(-g))) * u;  // silu(g)*u
        hbuf[(size_t)row * N + col] = hv;
        rmax = fmaxf(rmax, fabsf(hv));
      }
      // reduce |h| max across the 16 lanes holding this row's columns
#pragma unroll
      for (int off = 8; off > 0; off >>= 1)
        rmax = fmaxf(rmax, __shfl_xor(rmax, off, 64));
      if (l16 == 0)
        atomicMax(hmax + row, __float_as_int(rmax));  // nonneg f32: int-mono
    }
  }
}

// Down-projection GEMM: out = (hq @ Wd^T) * sh[m] * swd[n]
// 128x256 tile, per-wave 64x128 (acc[4][8] = 128 VGPR), same 3-buffer
// counted-vmcnt pipeline (also exactly 6 loads/thread/tile), 72 KB LDS.
__global__ __launch_bounds__(256, 2) void gemm2_kernel(
    const int8_t* __restrict__ hq, const int8_t* __restrict__ wdq,
    const float* __restrict__ sh, const float* __restrict__ swd,
    float* __restrict__ out, int M, int N, int K) {
  __shared__ __align__(16) int8_t sA[3][BM * BK];    // 3 x 8 KB
  __shared__ __align__(16) int8_t sB[3][BN2 * BK];   // 3 x 16 KB

  const int tid = threadIdx.x;
  const int lane = tid & 63;
  const int quad = lane >> 4;
  const int l16 = lane & 15;
  const int wave = tid >> 6;
  const int wm = wave >> 1;   // 0..1: 64-row group
  const int wn = wave & 1;    // 0..1: 128-col group

  const int nwg = gridDim.x * gridDim.y;
  const int lid = xcd_swizzle(blockIdx.y * gridDim.x + blockIdx.x, nwg);
  const int n0 = (lid % gridDim.x) * BN2;
  const int m0 = (lid / gridDim.x) * BM;

  const int T = K / BK;

  i32x4 acc[4][8] = {};

#define STAGE2(buf, kt)                                                       \
  {                                                                           \
    const int kk = (kt)*BK;                                                   \
    _Pragma("unroll") for (int it = 0; it < 2; ++it) {                        \
      const int c = tid + it * 256;                                           \
      const int r = c >> 2;                                                   \
      const int s = c & 3;                                                    \
      const int kc = ((s - (r >> 1)) & 3) << 4;                               \
      gl2lds16(hq + (size_t)(m0 + r) * K + (kk + kc), sA[buf] + c * 16);      \
    }                                                                         \
    _Pragma("unroll") for (int it = 0; it < 4; ++it) {                        \
      const int c = tid + it * 256;                                           \
      const int r = c >> 2;                                                   \
      const int s = c & 3;                                                    \
      const int kc = ((s - (r >> 1)) & 3) << 4;                               \
      gl2lds16(wdq + (size_t)(n0 + r) * K + (kk + kc), sB[buf] + c * 16);     \
    }                                                                         \
  }

  STAGE2(0, 0);
  STAGE2(1, 1);
  STAGE2(2, 2);

  for (int t = 0; t < T; ++t) {
    wait_tile(t, T);
    const int cur = t % 3;

    i32x4 af[4];
#pragma unroll
    for (int i = 0; i < 4; ++i) {
      const int ar = wm * 64 + i * 16 + l16;
      af[i] = *(const i32x4*)(sA[cur] + ar * BK + (((quad + (ar >> 1)) & 3) << 4));
    }
    __builtin_amdgcn_s_setprio(1);
#pragma unroll
    for (int j = 0; j < 8; ++j) {
      const int br = wn * 128 + j * 16 + l16;
      i32x4 bf = *(const i32x4*)(sB[cur] + br * BK + (((quad + (br >> 1)) & 3) << 4));
#pragma unroll
      for (int i = 0; i < 4; ++i)
        acc[i][j] = __builtin_amdgcn_mfma_i32_16x16x64_i8(af[i], bf, acc[i][j], 0, 0, 0);
    }
    __builtin_amdgcn_s_setprio(0);

    asm volatile("" ::: "memory");
    __builtin_amdgcn_s_barrier();
    asm volatile("" ::: "memory");
    if (t + 3 < T) STAGE2(cur, t + 3);
  }
#undef STAGE2

  float sn[8];
#pragma unroll
  for (int j = 0; j < 8; ++j) sn[j] = swd[n0 + wn * 128 + j * 16 + l16];
#pragma unroll
  for (int i = 0; i < 4; ++i) {
#pragma unroll
    for (int r = 0; r < 4; ++r) {
      const int row = m0 + wm * 64 + i * 16 + quad * 4 + r;
      const float s_m = sh[row];
#pragma unroll
      for (int j = 0; j < 8; ++j) {
        const int col = n0 + wn * 128 + j * 16 + l16;
        out[(size_t)row * N + col] = (float)acc[i][j][r] * s_m * sn[j];
      }
    }
  }
}

extern "C" void kernel_launch(void* const* d_in, const int* in_sizes, int n_in,
                              void* d_out, int out_size, void* d_ws, size_t ws_size,
                              hipStream_t stream) {
  const float* x  = (const float*)d_in[0];   // [2,2048,4096]
  const float* Wg = (const float*)d_in[1];   // [11008,4096]
  const float* Wu = (const float*)d_in[2];   // [11008,4096]
  const float* Wd = (const float*)d_in[3];   // [4096,11008]
  float* out = (float*)d_out;                // [2,2048,4096] f32

  const int M = 4096;   // B*S
  const int D = 4096;
  const int F = 11008;

  // workspace layout (~378 MB total), all offsets 16B-aligned
  uint8_t* ws = (uint8_t*)d_ws;
  size_t off = 0;
  int8_t* xq  = (int8_t*)(ws + off); off += (size_t)M * D;      // 16 MB
  int8_t* wgq = (int8_t*)(ws + off); off += (size_t)F * D;      // 45 MB
  int8_t* wuq = (int8_t*)(ws + off); off += (size_t)F * D;      // 45 MB
  int8_t* wdq = (int8_t*)(ws + off); off += (size_t)D * F;      // 45 MB
  int8_t* hq  = (int8_t*)(ws + off); off += (size_t)M * F;      // 45 MB
  float* hbuf = (float*)(ws + off);  off += (size_t)M * F * 4;  // 180 MB
  float* sx   = (float*)(ws + off);  off += (size_t)M * 4;
  float* swg  = (float*)(ws + off);  off += (size_t)F * 4;
  float* swu  = (float*)(ws + off);  off += (size_t)F * 4;
  float* swd  = (float*)(ws + off);  off += (size_t)D * 4;
  float* sh   = (float*)(ws + off);  off += (size_t)M * 4;
  int*   hmax = (int*)(ws + off);    off += (size_t)M * 4;

  // One merged quant launch for x, Wg, Wu, Wd (also zeroes hmax).
  hipLaunchKernelGGL(quant_all_kernel, dim3(M + F + F + D), dim3(256), 0,
                     stream, x, Wg, Wu, Wd, xq, wgq, wuq, wdq,
                     sx, swg, swu, swd, hmax);
  hipLaunchKernelGGL(gemm1_kernel, dim3(F / BN, M / BM), dim3(256), 0, stream,
                     xq, wgq, wuq, sx, swg, swu, hbuf, hmax, M, F, D);
  hipLaunchKernelGGL(quant_h_kernel, dim3(M), dim3(256), 0, stream,
                     hbuf, hq, sh, hmax, F);
  hipLaunchKernelGGL(gemm2_kernel, dim3(D / BN2, M / BM), dim3(256), 0, stream,
                     hq, wdq, sh, swd, out, M, D, F);
}